// Round 19
// baseline (57.313 us; speedup 1.0000x reference)
//
#include <hip/hip_runtime.h>
#include <hip/hip_bf16.h>

#define NTAGS 64
#define START_TAG 1
#define END_TAG 63
#define LN2F 0.69314718055994530942f
#define NSEG 128
#define SEGL 4

typedef float v4f __attribute__((ext_vector_type(4)));
typedef short s16x8 __attribute__((ext_vector_type(8)));

static __device__ __forceinline__ unsigned short f2bfu(float x) {
    union { __hip_bfloat16 h; unsigned short s; } u;
    u.h = __float2bfloat16(x);
    return u.s;
}
static __device__ __forceinline__ unsigned int packbf(float lo, float hi) {
    return (unsigned int)f2bfu(lo) | ((unsigned int)f2bfu(hi) << 16);
}
// convention-proof partner fetch (R10-R18 validated): rr0+rr1-v == v[l^K]
static __device__ __forceinline__ float xor16_get(float send) {
    auto rr = __builtin_amdgcn_permlane16_swap(__float_as_uint(send), __float_as_uint(send),
                                               false, false);
    return (__uint_as_float((unsigned)rr[0]) + __uint_as_float((unsigned)rr[1])) - send;
}
static __device__ __forceinline__ float xor32_get(float send) {
    auto rr = __builtin_amdgcn_permlane32_swap(__float_as_uint(send), __float_as_uint(send),
                                               false, false);
    return (__uint_as_float((unsigned)rr[0]) + __uint_as_float((unsigned)rr[1])) - send;
}
static __device__ __forceinline__ v4f max4(v4f a, v4f b) {
    return __builtin_elementwise_max(a, b);
}
// async global->LDS, 16B per lane; LDS dest = wave-uniform base + lane*16B
static __device__ __forceinline__ void gl_lds_16(const float* g, float* lds_base) {
    __builtin_amdgcn_global_load_lds(
        (const __attribute__((address_space(1))) void*)g,
        (__attribute__((address_space(3))) void*)lds_base, 16, 0, 0);
}

// ---------------------------------------------------------------------------
// Setup: bf16 transition fragments (both directions, frag-major coalesced)
// and u[j] = exp(trans[j][END]).
// ---------------------------------------------------------------------------
__global__ __launch_bounds__(64) void crf_setup(const float* __restrict__ trans,
                                                s16x8* __restrict__ afws,
                                                float* __restrict__ uws) {
    const int lane = threadIdx.x;
    const int c = lane & 15, g = lane >> 4;
#pragma unroll
    for (int m = 0; m < 4; ++m)
#pragma unroll
        for (int kk = 0; kk < 2; ++kk) {
            s16x8 vf, vb;
#pragma unroll
            for (int e = 0; e < 8; ++e) {
                vf[e] = (short)f2bfu(__expf(trans[(32 * kk + 8 * g + e) * NTAGS + 16 * m + c]));
                vb[e] = (short)f2bfu(__expf(trans[(16 * m + c) * NTAGS + 32 * kk + 8 * g + e]));
            }
            afws[(0 * 8 + 2 * m + kk) * 64 + lane] = vf;
            afws[(1 * 8 + 2 * m + kk) * 64 + lane] = vb;
        }
    uws[lane] = __expf(trans[lane * NTAGS + END_TAG]);
}

// ---------------------------------------------------------------------------
// Fused fwd+bwd MFMA chain, NSEG=128 segments of SEGL=4 steps.
// One wave = one (segment, 16-batch tile); feats for the segment staged by
// 16 fire-and-forget global_load_lds ops, each a FULL 1KB CONTIGUOUS block
// (batch i, 4 t's x 64 tags) with XOR-pre-swizzled per-lane source
// (tagquad ^= i&7) so the linear LDS image [batch][t][tagquad^swz] gives
// bank-balanced ds_read_b128 in the step loop (8 lanes/bank-quad = LDS
// floor). Single vmcnt(0); then 4 fused fwd+bwd MFMA steps (R16-verified
// math: D->B via 4x permlane32_swap + 4x permlane16_swap; no in-loop
// rescale; one exact power-of-2 rescale per direction at output).
// ---------------------------------------------------------------------------
__global__ __launch_bounds__(64) void crf_chains(const float* __restrict__ feats,
                                                 const float* __restrict__ mask,
                                                 const int* __restrict__ tags,
                                                 const float* __restrict__ trans,
                                                 const s16x8* __restrict__ afws,
                                                 const float* __restrict__ uws,
                                                 float* __restrict__ seg,
                                                 int* __restrict__ es,
                                                 float* __restrict__ gs,
                                                 int S, int B, int nchain) {
    const int bid = (int)blockIdx.x;
    const int lane = threadIdx.x;

    if (bid >= nchain) {
        // ---- gold path score: one wave per batch ----
        const int b = bid - nchain;
        const float* fb = feats + (size_t)b * S * NTAGS;
        const float* mb = mask + (size_t)b * S;
        const int* tb = tags + (size_t)b * S;
        float acc = 0.f, msum = 0.f;
        for (int t = lane; t < S; t += 64) {
            int cur = tb[t];
            int prev = (t == 0) ? START_TAG : tb[t - 1];
            float m = mb[t];
            acc += (fb[t * NTAGS + cur] + trans[prev * NTAGS + cur]) * m;
            msum += m;
        }
#pragma unroll
        for (int sh = 32; sh >= 1; sh >>= 1) {
            acc += __shfl_xor(acc, sh);
            msum += __shfl_xor(msum, sh);
        }
        if (lane == 0) {
            int seq_end = (int)(msum + 0.5f) - 1;
            int last = (seq_end >= 0) ? tb[seq_end] : START_TAG;
            gs[b] = acc + trans[last * NTAGS + END_TAG];
        }
        return;
    }

    __shared__ __align__(16) float ebuf[16 * SEGL * 64];  // 16 KB: [batch][t][tq^swz]

    const int ntile = B / 16;
    const int segk = bid / ntile;
    const int tile = bid - segk * ntile;
    const int b0 = tile * 16;
    const int t0 = segk * SEGL;
    const int c = lane & 15, g = lane >> 4;
    const int tl = lane >> 4;   // staging: t-local index (0..3)
    const int tq = lane & 15;   // staging: tag-quad index

    // ---- staging: 16 x 1KB contiguous global_load_lds, source pre-swizzled
    // lane l of instr i fetches feats[b0+i][t0+tl][4*(tq^(i&7)) .. +3]
#pragma unroll
    for (int i = 0; i < 16; ++i) {
        const float* src = feats + ((size_t)(b0 + i) * S + t0 + tl) * NTAGS
                         + 4 * (tq ^ (i & 7));
        gl_lds_16(src, &ebuf[i * (SEGL * 64)]);  // dest linear: + lane*16B by HW
    }

    // A fragments for both directions (16 coalesced b128 loads)
    s16x8 Ff[4][2], Fb[4][2];
#pragma unroll
    for (int m = 0; m < 4; ++m)
#pragma unroll
        for (int kk = 0; kk < 2; ++kk) {
            Ff[m][kk] = afws[(2 * m + kk) * 64 + lane];
            Fb[m][kk] = afws[(8 + 2 * m + kk) * 64 + lane];
        }

    // masks for this tile (lane c's batch)
    float Mv[SEGL];
#pragma unroll
    for (int t = 0; t < SEGL; ++t) Mv[t] = mask[(size_t)(b0 + c) * S + t0 + t];

    // states: D0 = fwd, D1 = bwd (f32, MFMA D layout)
    v4f D0[4], D1[4];
#pragma unroll
    for (int m = 0; m < 4; ++m) D0[m] = (v4f){1.f, 1.f, 1.f, 1.f};
    if (segk == 0) {
#pragma unroll
        for (int m = 0; m < 4; ++m) D0[m] = (v4f){0.f, 0.f, 0.f, 0.f};
        if (g == 0) D0[0].y = 1.0f;  // tag 1 = START
    }
    if (segk == NSEG - 1) {
#pragma unroll
        for (int m = 0; m < 4; ++m) D1[m] = *(const v4f*)(uws + 16 * m + 4 * g);
    } else {
#pragma unroll
        for (int m = 0; m < 4; ++m) D1[m] = (v4f){1.f, 1.f, 1.f, 1.f};
    }

    asm volatile("s_waitcnt vmcnt(0)" ::: "memory");  // staging complete (1-wave block)

#define XFORM(up, bfv0, bfv1)                                                     \
    do {                                                                          \
        auto rA = __builtin_amdgcn_permlane32_swap(up[0][0], up[1][0], false, false); \
        auto rB = __builtin_amdgcn_permlane32_swap(up[0][1], up[1][1], false, false); \
        auto rC = __builtin_amdgcn_permlane32_swap(up[2][0], up[3][0], false, false); \
        auto rD = __builtin_amdgcn_permlane32_swap(up[2][1], up[3][1], false, false); \
        auto sA = __builtin_amdgcn_permlane16_swap((unsigned)rA[0], (unsigned)rA[1], false, false); \
        auto sB = __builtin_amdgcn_permlane16_swap((unsigned)rB[0], (unsigned)rB[1], false, false); \
        auto sC = __builtin_amdgcn_permlane16_swap((unsigned)rC[0], (unsigned)rC[1], false, false); \
        auto sD = __builtin_amdgcn_permlane16_swap((unsigned)rD[0], (unsigned)rD[1], false, false); \
        bfv0.d[0] = sA[0]; bfv0.d[1] = sB[0]; bfv0.d[2] = sA[1]; bfv0.d[3] = sB[1]; \
        bfv1.d[0] = sC[0]; bfv1.d[1] = sD[0]; bfv1.d[2] = sC[1]; bfv1.d[3] = sD[1]; \
    } while (0)

    // E read: batch c, step t, fragment n -> tags 16n+4g..+3 at
    // ebuf[c*(SEGL*64) + t*64 + 4*((4n+g)^(c&7))]
#define EREAD(Ex, t)                                                              \
    do {                                                                          \
        const float* Eb_ = &ebuf[c * (SEGL * 64) + (t) * 64];                     \
        _Pragma("unroll") for (int n = 0; n < 4; ++n) {                           \
            v4f rf = *(const v4f*)(Eb_ + 4 * ((4 * n + g) ^ (c & 7)));            \
            Ex[n] = (v4f){__expf(rf.x), __expf(rf.y), __expf(rf.z), __expf(rf.w)};\
        }                                                                         \
    } while (0)

#pragma unroll
    for (int s = 0; s < SEGL; ++s) {
        v4f Exf[4], Exb[4];
        EREAD(Exf, s);
        EREAD(Exb, SEGL - 1 - s);

        // ---- fwd step: D0 = (A^T D0) * E[s] (masked) ----
        {
            unsigned int up[4][2];
#pragma unroll
            for (int n = 0; n < 4; ++n) {
                up[n][0] = packbf(D0[n].x, D0[n].y);
                up[n][1] = packbf(D0[n].z, D0[n].w);
            }
            union { unsigned int d[4]; s16x8 v; } bf0, bf1;
            XFORM(up, bf0, bf1);
            v4f Dm[4];
#pragma unroll
            for (int m = 0; m < 4; ++m) {
                v4f z = (v4f){0.f, 0.f, 0.f, 0.f};
                Dm[m] = __builtin_amdgcn_mfma_f32_16x16x32_bf16(Ff[m][0], bf0.v, z, 0, 0, 0);
                Dm[m] = __builtin_amdgcn_mfma_f32_16x16x32_bf16(Ff[m][1], bf1.v, Dm[m], 0, 0, 0);
                Dm[m] = Dm[m] * Exf[m];
            }
            bool act = (Mv[s] != 0.0f);
#pragma unroll
            for (int m = 0; m < 4; ++m) D0[m] = act ? Dm[m] : D0[m];
        }

        // ---- bwd step: D1 = A (E[SEGL-1-s] * D1) (masked) ----
        {
            unsigned int up[4][2];
#pragma unroll
            for (int n = 0; n < 4; ++n) {
                v4f sv = D1[n] * Exb[n];
                up[n][0] = packbf(sv.x, sv.y);
                up[n][1] = packbf(sv.z, sv.w);
            }
            union { unsigned int d[4]; s16x8 v; } bf0, bf1;
            XFORM(up, bf0, bf1);
            v4f Dm[4];
#pragma unroll
            for (int m = 0; m < 4; ++m) {
                v4f z = (v4f){0.f, 0.f, 0.f, 0.f};
                Dm[m] = __builtin_amdgcn_mfma_f32_16x16x32_bf16(Fb[m][0], bf0.v, z, 0, 0, 0);
                Dm[m] = __builtin_amdgcn_mfma_f32_16x16x32_bf16(Fb[m][1], bf1.v, Dm[m], 0, 0, 0);
            }
            bool act = (Mv[SEGL - 1 - s] != 0.0f);
#pragma unroll
            for (int m = 0; m < 4; ++m) D1[m] = act ? Dm[m] : D1[m];
        }
    }
#undef EREAD
#undef XFORM

    // ---- epilogue: exact power-of-2 rescale + write (guarded per type) ----
    if (segk < NSEG - 1) {  // fwd type = segk (0..NSEG-2)
        int ex0 = 0;
        v4f mm = max4(max4(D0[0], D0[1]), max4(D0[2], D0[3]));
        float mx = fmaxf(fmaxf(mm.x, mm.y), fmaxf(mm.z, mm.w));
        mx = fmaxf(mx, xor16_get(mx));
        mx = fmaxf(mx, xor32_get(mx));
        int ef = (__float_as_int(mx) >> 23) & 0xFF;
        if (ef != 0) {
            ex0 = ef - 127;
#pragma unroll
            for (int m = 0; m < 4; ++m) {
                D0[m].x = ldexpf(D0[m].x, -ex0); D0[m].y = ldexpf(D0[m].y, -ex0);
                D0[m].z = ldexpf(D0[m].z, -ex0); D0[m].w = ldexpf(D0[m].w, -ex0);
            }
        }
        float* oc = seg + ((size_t)segk * B + b0 + c) * NTAGS;
#pragma unroll
        for (int m = 0; m < 4; ++m) *(v4f*)(oc + 16 * m + 4 * g) = D0[m];
        if (g == 0) es[(size_t)segk * B + b0 + c] = ex0;
    }
    if (segk > 0) {  // bwd type = (NSEG-2) + segk
        int ex1 = 0;
        v4f mm = max4(max4(D1[0], D1[1]), max4(D1[2], D1[3]));
        float mx = fmaxf(fmaxf(mm.x, mm.y), fmaxf(mm.z, mm.w));
        mx = fmaxf(mx, xor16_get(mx));
        mx = fmaxf(mx, xor32_get(mx));
        int ef = (__float_as_int(mx) >> 23) & 0xFF;
        if (ef != 0) {
            ex1 = ef - 127;
#pragma unroll
            for (int m = 0; m < 4; ++m) {
                D1[m].x = ldexpf(D1[m].x, -ex1); D1[m].y = ldexpf(D1[m].y, -ex1);
                D1[m].z = ldexpf(D1[m].z, -ex1); D1[m].w = ldexpf(D1[m].w, -ex1);
            }
        }
        const int type = (NSEG - 2) + segk;
        float* oc = seg + ((size_t)type * B + b0 + c) * NTAGS;
#pragma unroll
        for (int m = 0; m < 4; ++m) *(v4f*)(oc + 16 * m + 4 * g) = D1[m];
        if (g == 0) es[(size_t)type * B + b0 + c] = ex1;
    }
}

// ---------------------------------------------------------------------------
// Lane-parallel bridging, one wave per batch; NSEG-1 = 127 bridges:
// lane j<63 handles bridges j+1 and j+64; lane 63 handles bridge 127 and
// the es_bwd[NSEG-1] term.
//   contrib(g) = ln(l_g . r_{g-1}) + ln2*es_fwd[g-1]
//              - (g <= NSEG-2 ? ln(sum l_g) : 0)
// r_{g-1} = seg[g-1], l_g = seg[(NSEG-2)+g]. Probe-l exponents cancel.
// ---------------------------------------------------------------------------
__global__ __launch_bounds__(512) void crf_finish(const float* __restrict__ seg,
                                                  const int* __restrict__ es,
                                                  const float* __restrict__ gs,
                                                  float* __restrict__ scores, int B) {
    const int tid = threadIdx.x;
    const int wave = tid >> 6, lane = tid & 63;
    const int b = blockIdx.x * 8 + wave;
    if (b >= B) return;

    float contrib = 0.f;
#pragma unroll
    for (int rep = 0; rep < 2; ++rep) {
        int g = (rep == 0) ? (lane + 1) : (lane + 64);
        if (g <= NSEG - 1 && (rep == 0 ? lane < 63 : true) && (rep == 0 || lane < 64)) {
            if (rep == 0 && lane >= 63) continue;
            const float* rv = seg + ((size_t)(g - 1) * B + b) * NTAGS;
            const float* lv = seg + ((size_t)((NSEG - 2) + g) * B + b) * NTAGS;
            v4f dacc = (v4f){0.f, 0.f, 0.f, 0.f};
            v4f sacc = dacc;
#pragma unroll
            for (int i = 0; i < 16; ++i) {
                v4f rr = *(const v4f*)(rv + 4 * i);
                v4f ll = *(const v4f*)(lv + 4 * i);
                dacc = __builtin_elementwise_fma(ll, rr, dacc);
                sacc = sacc + ll;
            }
            float dot = (dacc.x + dacc.y) + (dacc.z + dacc.w);
            float sl = (sacc.x + sacc.y) + (sacc.z + sacc.w);
            contrib += __logf(dot) + (float)es[(size_t)(g - 1) * B + b] * LN2F;
            if (g <= NSEG - 2) contrib -= __logf(sl);
        }
    }
    if (lane == 63)
        contrib += (float)es[(size_t)((NSEG - 2) + (NSEG - 1)) * B + b] * LN2F;
#pragma unroll
    for (int sh = 32; sh >= 1; sh >>= 1) contrib += __shfl_xor(contrib, sh);
    if (lane == 0) scores[b] = contrib - gs[b];
}

__global__ __launch_bounds__(1024) void crf_mean(const float* __restrict__ scores,
                                                 float* __restrict__ out, int B) {
    const int tid = threadIdx.x;
    float a = 0.f;
    for (int i = tid; i < B; i += 1024) a += scores[i];
#pragma unroll
    for (int sh = 32; sh >= 1; sh >>= 1) a += __shfl_xor(a, sh);
    __shared__ float buf[16];
    if ((tid & 63) == 0) buf[tid >> 6] = a;
    __syncthreads();
    if (tid == 0) {
        float s = 0.f;
#pragma unroll
        for (int i = 0; i < 16; ++i) s += buf[i];
        out[0] = s / (float)B;
    }
}

extern "C" void kernel_launch(void* const* d_in, const int* in_sizes, int n_in,
                              void* d_out, int out_size, void* d_ws, size_t ws_size,
                              hipStream_t stream) {
    const float* feats = (const float*)d_in[0];
    const float* mask  = (const float*)d_in[1];
    const int*   tags  = (const int*)d_in[2];
    const float* trans = (const float*)d_in[3];
    float* out = (float*)d_out;

    const int S = 512;              // reference shape
    const int B = in_sizes[1] / S;  // mask is (B,S)
    const int nchain = NSEG * (B / 16);  // fused fwd+bwd per (seg, tile)
    const int ntypes = 2 * (NSEG - 1);   // 254

    float* afws = (float*)d_ws;                           // 4096 floats (16 KB)
    float* uws = afws + 4096;                             // 64
    float* seg = uws + 64;                                // [254][B][64]
    int* es = (int*)(seg + (size_t)ntypes * B * NTAGS);   // [254][B]
    float* gs = (float*)(es + ntypes * B);                // [B]
    float* scores = gs + B;                               // [B]

    crf_setup<<<1, 64, 0, stream>>>(trans, (s16x8*)afws, uws);
    crf_chains<<<nchain + B, 64, 0, stream>>>(feats, mask, tags, trans,
                                              (const s16x8*)afws, uws,
                                              seg, es, gs, S, B, nchain);
    crf_finish<<<(B + 7) / 8, 512, 0, stream>>>(seg, es, gs, scores, B);
    crf_mean<<<1, 1024, 0, stream>>>(scores, out, B);
}